// Round 4
// baseline (342.307 us; speedup 1.0000x reference)
//
#include <hip/hip_runtime.h>
#include <hip/hip_bf16.h>

#define HWDIM 512
#define NWIN 50        // windows per dim: (512-20)/10 + 1
#define NT 51          // 10x10 tiles per dim covering rows/cols 0..509
#define NBC 48         // B*C = 16*3
#define EPSV 1e-5f

// ws layout (floats):
//   [0..47]    int planeCnt[48]
//   [48]       int globalCnt
//   [64..111]  float acc[48]      (per-plane ssq/total ratio)
//   [128..]    float tiles[48*51*51*3]
__global__ void zero_kernel(int* cnts) {
    int t = threadIdx.x;
    if (t < NBC + 1) cnts[t] = 0;
}

// ---------------------------------------------------------------------------
// Fused: tile sums -> (last stripe-block per plane) window combine ->
//        (last plane) final mean.
// Tile phase: thread t: col4 = t&127 (cols 4c..4c+3), row-half rh = t>>7,
// rows 2*it+rh, it=0..4. Pattern repeats every 5 float4s per 2 tiles;
// f=c4%5: f=0,1 all in tile 2k; f=2 splits lo/hi; f=3,4 all in tile 2k+1.
// ---------------------------------------------------------------------------
__global__ __launch_bounds__(256) void fused_kernel(const float* __restrict__ C,
                                                    const float* __restrict__ E,
                                                    const float* __restrict__ M,
                                                    int* __restrict__ cnts,
                                                    float* __restrict__ acc,
                                                    float* __restrict__ tiles,
                                                    float* __restrict__ out) {
    int blk   = blockIdx.x;        // plane*NT + ty
    int plane = blk / NT;
    int ty    = blk % NT;
    int t     = threadIdx.x;
    int c4    = t & 127;
    int rh    = t >> 7;
    bool isf2 = ((c4 % 5) == 2);

    size_t base = ((size_t)plane * HWDIM + (size_t)ty * 10 + rh) * HWDIM + 4 * c4;

    // ---- batched loads: force all 15 in flight before any consumption ----
    float4 cv[5], ev[5], mv[5];
    #pragma unroll
    for (int it = 0; it < 5; ++it) {
        size_t o = base + (size_t)(2 * it) * HWDIM;
        cv[it] = *(const float4*)(C + o);
        ev[it] = *(const float4*)(E + o);
        mv[it] = *(const float4*)(M + o);
    }
    __builtin_amdgcn_sched_barrier(0);   // loads may not sink past this

    float s01[3] = {0.f, 0.f, 0.f};
    float s23[3] = {0.f, 0.f, 0.f};
    #pragma unroll
    for (int it = 0; it < 5; ++it) {
        float4 c = cv[it], e = ev[it], m = mv[it];
        float mcx = m.x * c.x, mcy = m.y * c.y, mcz = m.z * c.z, mcw = m.w * c.w;
        float mex = m.x * e.x, mey = m.y * e.y, mez = m.z * e.z, mew = m.w * e.w;
        s01[0] = fmaf(mcx, c.x, s01[0]); s01[0] = fmaf(mcy, c.y, s01[0]);
        s01[1] = fmaf(mcx, e.x, s01[1]); s01[1] = fmaf(mcy, e.y, s01[1]);
        s01[2] = fmaf(mex, e.x, s01[2]); s01[2] = fmaf(mey, e.y, s01[2]);
        s23[0] = fmaf(mcz, c.z, s23[0]); s23[0] = fmaf(mcw, c.w, s23[0]);
        s23[1] = fmaf(mcz, e.z, s23[1]); s23[1] = fmaf(mcw, e.w, s23[1]);
        s23[2] = fmaf(mez, e.z, s23[2]); s23[2] = fmaf(mew, e.w, s23[2]);
    }

    __shared__ float lds[256 * 6];
    #pragma unroll
    for (int comp = 0; comp < 3; ++comp) {
        float lo = s01[comp] + (isf2 ? 0.f : s23[comp]);
        float hi = isf2 ? s23[comp] : 0.f;
        lds[t * 6 + comp]     = lo;
        lds[t * 6 + 3 + comp] = hi;
    }
    __syncthreads();

    if (t < NT * 3) {              // 153 threads: one per (tile, component)
        int tx = t / 3, comp = t % 3;
        int k  = tx >> 1;
        float s;
        if ((tx & 1) == 0) {
            int b = 5 * k;
            s = lds[b * 6 + comp] + lds[(b + 1) * 6 + comp] + lds[(b + 2) * 6 + comp]
              + lds[(b + 128) * 6 + comp] + lds[(b + 129) * 6 + comp] + lds[(b + 130) * 6 + comp];
        } else {
            int b = 5 * k + 2;
            s = lds[b * 6 + 3 + comp] + lds[(b + 1) * 6 + comp] + lds[(b + 2) * 6 + comp]
              + lds[(b + 128) * 6 + 3 + comp] + lds[(b + 129) * 6 + comp] + lds[(b + 130) * 6 + comp];
        }
        tiles[((size_t)blk * NT + tx) * 3 + comp] = s;
    }

    // ---- release our tile sums; last stripe-block of the plane continues ----
    __threadfence();
    __shared__ int sflag;
    if (t == 0) sflag = (atomicAdd(&cnts[plane], 1) == NT - 1);
    __syncthreads();
    if (!sflag) return;
    __threadfence();               // acquire: invalidate L1/L2 before reading peers' tiles

    // ---- window phase for this plane ----
    const float* tp = tiles + (size_t)plane * NT * NT * 3;
    float ssq = 0.0f, tot = 0.0f;
    for (int w = t; w < NWIN * NWIN; w += 256) {
        int wy = w / NWIN, wx = w % NWIN;
        const float* t00 = tp + ((size_t)wy * NT + wx) * 3;
        const float* t10 = t00 + (size_t)NT * 3;
        float s_cc = t00[0] + t00[3] + t10[0] + t10[3];
        float s_ce = t00[1] + t00[4] + t10[1] + t10[4];
        float s_ee = t00[2] + t00[5] + t10[2] + t10[5];
        float a2v = (s_ee > EPSV) ? (s_ce * s_ce / s_ee) : 0.0f;
        ssq += s_cc - a2v;
        tot += s_cc;
    }
    #pragma unroll
    for (int d = 1; d < 64; d <<= 1) {
        ssq += __shfl_xor(ssq, d);
        tot += __shfl_xor(tot, d);
    }
    __shared__ float sr[8];
    int lane = t & 63, wave = t >> 6;
    if (lane == 0) { sr[wave] = ssq; sr[4 + wave] = tot; }
    __syncthreads();
    if (t == 0) {
        float S = sr[0] + sr[1] + sr[2] + sr[3];
        float T = sr[4] + sr[5] + sr[6] + sr[7];
        acc[plane] = S / T;
        __threadfence();
        sflag = (atomicAdd(&cnts[NBC], 1) == NBC - 1);
    }
    __syncthreads();
    if (!sflag) return;
    __threadfence();               // acquire before reading peers' acc

    // ---- final phase: mean of 48 ratios ----
    if (t < 64) {
        const volatile float* vacc = acc;
        float r = (t < NBC) ? vacc[t] : 0.0f;
        #pragma unroll
        for (int d = 1; d < 64; d <<= 1) r += __shfl_xor(r, d);
        if (t == 0) out[0] = r / (float)NBC;
    }
}

extern "C" void kernel_launch(void* const* d_in, const int* in_sizes, int n_in,
                              void* d_out, int out_size, void* d_ws, size_t ws_size,
                              hipStream_t stream) {
    const float* correct  = (const float*)d_in[0];
    const float* estimate = (const float*)d_in[1];
    const float* mask     = (const float*)d_in[2];
    float* out = (float*)d_out;

    int*   cnts  = (int*)d_ws;                   // 49 ints
    float* acc   = (float*)d_ws + 64;            // 48 floats
    float* tiles = (float*)d_ws + 128;           // 48*51*51*3 floats ~ 1.5 MB

    zero_kernel<<<1, 64, 0, stream>>>(cnts);
    fused_kernel<<<NBC * NT, 256, 0, stream>>>(correct, estimate, mask,
                                               cnts, acc, tiles, out);
}

// Round 5
// 38.058 us; speedup vs baseline: 8.9944x; 8.9944x over previous
//
#include <hip/hip_runtime.h>
#include <hip/hip_bf16.h>

#define HWDIM 512
#define NWIN 50        // windows per dim: (512-20)/10 + 1
#define NT 51          // 10x10 tiles per dim covering rows/cols 0..509
#define NBC 48         // B*C = 16*3
#define EPSV 1e-5f

// ws layout (floats): [0] int cnt; [64..111] float acc[48]; [128..] tiles[48*51*51*3]

// ---------------------------------------------------------------------------
// Pass 1: per-(plane, 10-row stripe) tile sums, float4 loads, batched MLP.
// Thread t: col4 = t&127 (cols 4c..4c+3), row-half rh = t>>7, rows 2*it+rh.
// f=c4%5: f=0,1 all in tile 2k; f=2 splits lo/hi; f=3,4 all in tile 2k+1.
// Block 0 also zeroes the last-arriver counter used by pass 2 (visible at
// kernel boundary).
// ---------------------------------------------------------------------------
__global__ __launch_bounds__(256) void tile_kernel(const float* __restrict__ C,
                                                   const float* __restrict__ E,
                                                   const float* __restrict__ M,
                                                   float* __restrict__ tiles,
                                                   int* __restrict__ cnt) {
    int blk   = blockIdx.x;        // plane*NT + ty
    if (blk == 0 && threadIdx.x == 0) *cnt = 0;

    int plane = blk / NT;
    int ty    = blk % NT;
    int t     = threadIdx.x;
    int c4    = t & 127;
    int rh    = t >> 7;
    bool isf2 = ((c4 % 5) == 2);

    size_t base = ((size_t)plane * HWDIM + (size_t)ty * 10 + rh) * HWDIM + 4 * c4;

    float4 cv[5], ev[5], mv[5];
    #pragma unroll
    for (int it = 0; it < 5; ++it) {
        size_t o = base + (size_t)(2 * it) * HWDIM;
        cv[it] = *(const float4*)(C + o);
        ev[it] = *(const float4*)(E + o);
        mv[it] = *(const float4*)(M + o);
    }
    __builtin_amdgcn_sched_barrier(0);

    float s01[3] = {0.f, 0.f, 0.f};
    float s23[3] = {0.f, 0.f, 0.f};
    #pragma unroll
    for (int it = 0; it < 5; ++it) {
        float4 c = cv[it], e = ev[it], m = mv[it];
        float mcx = m.x * c.x, mcy = m.y * c.y, mcz = m.z * c.z, mcw = m.w * c.w;
        float mex = m.x * e.x, mey = m.y * e.y, mez = m.z * e.z, mew = m.w * e.w;
        s01[0] = fmaf(mcx, c.x, s01[0]); s01[0] = fmaf(mcy, c.y, s01[0]);
        s01[1] = fmaf(mcx, e.x, s01[1]); s01[1] = fmaf(mcy, e.y, s01[1]);
        s01[2] = fmaf(mex, e.x, s01[2]); s01[2] = fmaf(mey, e.y, s01[2]);
        s23[0] = fmaf(mcz, c.z, s23[0]); s23[0] = fmaf(mcw, c.w, s23[0]);
        s23[1] = fmaf(mcz, e.z, s23[1]); s23[1] = fmaf(mcw, e.w, s23[1]);
        s23[2] = fmaf(mez, e.z, s23[2]); s23[2] = fmaf(mew, e.w, s23[2]);
    }

    __shared__ float lds[256 * 6];
    #pragma unroll
    for (int comp = 0; comp < 3; ++comp) {
        float lo = s01[comp] + (isf2 ? 0.f : s23[comp]);
        float hi = isf2 ? s23[comp] : 0.f;
        lds[t * 6 + comp]     = lo;
        lds[t * 6 + 3 + comp] = hi;
    }
    __syncthreads();

    if (t < NT * 3) {              // 153 threads: one per (tile, component)
        int tx = t / 3, comp = t % 3;
        int k  = tx >> 1;
        float s;
        if ((tx & 1) == 0) {
            int b = 5 * k;
            s = lds[b * 6 + comp] + lds[(b + 1) * 6 + comp] + lds[(b + 2) * 6 + comp]
              + lds[(b + 128) * 6 + comp] + lds[(b + 129) * 6 + comp] + lds[(b + 130) * 6 + comp];
        } else {
            int b = 5 * k + 2;
            s = lds[b * 6 + 3 + comp] + lds[(b + 1) * 6 + comp] + lds[(b + 2) * 6 + comp]
              + lds[(b + 128) * 6 + 3 + comp] + lds[(b + 129) * 6 + comp] + lds[(b + 130) * 6 + comp];
        }
        tiles[((size_t)blk * NT + tx) * 3 + comp] = s;
    }
}

// ---------------------------------------------------------------------------
// Pass 2 (fused window + final): 48 blocks, one per plane. Each computes its
// plane's ratio; the last-arriving block (48 release fences total, ONE
// acquire) computes the deterministic fixed-order 48-way mean.
// ---------------------------------------------------------------------------
__global__ __launch_bounds__(256) void window_final_kernel(const float* __restrict__ tiles,
                                                           float* __restrict__ acc,
                                                           int* __restrict__ cnt,
                                                           float* __restrict__ out) {
    int plane = blockIdx.x;
    int t     = threadIdx.x;
    const float* tp = tiles + (size_t)plane * NT * NT * 3;

    float ssq = 0.0f, tot = 0.0f;
    for (int w = t; w < NWIN * NWIN; w += 256) {
        int wy = w / NWIN, wx = w % NWIN;
        const float* t00 = tp + ((size_t)wy * NT + wx) * 3;
        const float* t10 = t00 + (size_t)NT * 3;
        float s_cc = t00[0] + t00[3] + t10[0] + t10[3];
        float s_ce = t00[1] + t00[4] + t10[1] + t10[4];
        float s_ee = t00[2] + t00[5] + t10[2] + t10[5];
        float a2v = (s_ee > EPSV) ? (s_ce * s_ce / s_ee) : 0.0f;
        ssq += s_cc - a2v;
        tot += s_cc;
    }

    #pragma unroll
    for (int d = 1; d < 64; d <<= 1) {
        ssq += __shfl_xor(ssq, d);
        tot += __shfl_xor(tot, d);
    }
    __shared__ float sr[8];
    __shared__ int   sflag;
    int lane = t & 63, wave = t >> 6;
    if (lane == 0) { sr[wave] = ssq; sr[4 + wave] = tot; }
    __syncthreads();

    if (t == 0) {
        float S = sr[0] + sr[1] + sr[2] + sr[3];
        float T = sr[4] + sr[5] + sr[6] + sr[7];
        acc[plane] = S / T;
        __threadfence();                     // release acc[plane]
        sflag = (atomicAdd(cnt, 1) == NBC - 1);
    }
    __syncthreads();
    if (!sflag) return;

    __threadfence();                         // acquire peers' acc
    if (t < 64) {
        float r = (t < NBC) ? *(volatile const float*)(acc + t) : 0.0f;
        #pragma unroll
        for (int d = 1; d < 64; d <<= 1) r += __shfl_xor(r, d);
        if (t == 0) out[0] = r / (float)NBC;
    }
}

extern "C" void kernel_launch(void* const* d_in, const int* in_sizes, int n_in,
                              void* d_out, int out_size, void* d_ws, size_t ws_size,
                              hipStream_t stream) {
    const float* correct  = (const float*)d_in[0];
    const float* estimate = (const float*)d_in[1];
    const float* mask     = (const float*)d_in[2];
    float* out = (float*)d_out;

    int*   cnt   = (int*)d_ws;                   // 1 int
    float* acc   = (float*)d_ws + 64;            // 48 floats
    float* tiles = (float*)d_ws + 128;           // 48*51*51*3 floats ~ 1.5 MB

    tile_kernel<<<NBC * NT, 256, 0, stream>>>(correct, estimate, mask, tiles, cnt);
    window_final_kernel<<<NBC, 256, 0, stream>>>(tiles, acc, cnt, out);
}

// Round 6
// 36.986 us; speedup vs baseline: 9.2551x; 1.0290x over previous
//
#include <hip/hip_runtime.h>
#include <hip/hip_bf16.h>

#define HWDIM 512
#define NWIN 50        // windows per dim: (512-20)/10 + 1
#define NT 51          // 10x10 tiles per dim covering rows/cols 0..509
#define NBC 48         // B*C = 16*3
#define NSTRIPE (NBC * NT)   // 2448
#define GRID1 (NSTRIPE / 2)  // 1224 blocks, 2 stripes each (uniform)
#define EPSV 1e-5f

// ws layout (floats): [0] int cnt; [64..111] float acc[48]; [128..] tiles[48*51*51*3]

// ---------------------------------------------------------------------------
// Pass 1: per-(plane, 10-row stripe) tile sums; 2 stripes per block (uniform
// grid, no ramp-down tail). Thread t: col4 = t&127 (cols 4c..4c+3), row-half
// rh = t>>7, rows 2*it+rh. Tile-split pattern repeats every 5 float4s per 2
// tiles; f=c4%5: f=0,1 all in tile 2k; f=2 splits lo/hi; f=3,4 in tile 2k+1.
// ---------------------------------------------------------------------------
__global__ __launch_bounds__(256) void tile_kernel(const float* __restrict__ C,
                                                   const float* __restrict__ E,
                                                   const float* __restrict__ M,
                                                   float* __restrict__ tiles,
                                                   int* __restrict__ cnt) {
    int t = threadIdx.x;
    if (blockIdx.x == 0 && t == 0) *cnt = 0;   // for pass-2 last-arriver

    int c4    = t & 127;
    int rh    = t >> 7;
    bool isf2 = ((c4 % 5) == 2);

    __shared__ float lds[2][256 * 6];

    #pragma unroll
    for (int half = 0; half < 2; ++half) {
        int s     = blockIdx.x + half * GRID1;   // stripe id = plane*NT + ty
        int plane = s / NT;
        int ty    = s % NT;
        size_t base = ((size_t)plane * HWDIM + (size_t)ty * 10 + rh) * HWDIM + 4 * c4;

        float4 cv[5], ev[5], mv[5];
        #pragma unroll
        for (int it = 0; it < 5; ++it) {
            size_t o = base + (size_t)(2 * it) * HWDIM;
            cv[it] = *(const float4*)(C + o);
            ev[it] = *(const float4*)(E + o);
            mv[it] = *(const float4*)(M + o);
        }

        float s01[3] = {0.f, 0.f, 0.f};
        float s23[3] = {0.f, 0.f, 0.f};
        #pragma unroll
        for (int it = 0; it < 5; ++it) {
            float4 c = cv[it], e = ev[it], m = mv[it];
            float mcx = m.x * c.x, mcy = m.y * c.y, mcz = m.z * c.z, mcw = m.w * c.w;
            float mex = m.x * e.x, mey = m.y * e.y, mez = m.z * e.z, mew = m.w * e.w;
            s01[0] = fmaf(mcx, c.x, s01[0]); s01[0] = fmaf(mcy, c.y, s01[0]);
            s01[1] = fmaf(mcx, e.x, s01[1]); s01[1] = fmaf(mcy, e.y, s01[1]);
            s01[2] = fmaf(mex, e.x, s01[2]); s01[2] = fmaf(mey, e.y, s01[2]);
            s23[0] = fmaf(mcz, c.z, s23[0]); s23[0] = fmaf(mcw, c.w, s23[0]);
            s23[1] = fmaf(mcz, e.z, s23[1]); s23[1] = fmaf(mcw, e.w, s23[1]);
            s23[2] = fmaf(mez, e.z, s23[2]); s23[2] = fmaf(mew, e.w, s23[2]);
        }

        #pragma unroll
        for (int comp = 0; comp < 3; ++comp) {
            float lo = s01[comp] + (isf2 ? 0.f : s23[comp]);
            float hi = isf2 ? s23[comp] : 0.f;
            lds[half][t * 6 + comp]     = lo;
            lds[half][t * 6 + 3 + comp] = hi;
        }
    }
    __syncthreads();

    // 306 (tile, comp, half) outputs; threads 0..49 take two.
    for (int tt = t; tt < 2 * NT * 3; tt += 256) {
        int half = tt / (NT * 3);
        int u    = tt % (NT * 3);
        int tx   = u / 3, comp = u % 3;
        int k    = tx >> 1;
        const float* L = lds[half];
        float sum;
        if ((tx & 1) == 0) {
            int b = 5 * k;
            sum = L[b * 6 + comp] + L[(b + 1) * 6 + comp] + L[(b + 2) * 6 + comp]
                + L[(b + 128) * 6 + comp] + L[(b + 129) * 6 + comp] + L[(b + 130) * 6 + comp];
        } else {
            int b = 5 * k + 2;
            sum = L[b * 6 + 3 + comp] + L[(b + 1) * 6 + comp] + L[(b + 2) * 6 + comp]
                + L[(b + 128) * 6 + 3 + comp] + L[(b + 129) * 6 + comp] + L[(b + 130) * 6 + comp];
        }
        int s = blockIdx.x + half * GRID1;
        tiles[((size_t)s * NT + tx) * 3 + comp] = sum;
    }
}

// ---------------------------------------------------------------------------
// Pass 2 (fused window + final): 48 blocks, one per plane; last-arriving
// block computes the deterministic fixed-order 48-way mean.
// ---------------------------------------------------------------------------
__global__ __launch_bounds__(256) void window_final_kernel(const float* __restrict__ tiles,
                                                           float* __restrict__ acc,
                                                           int* __restrict__ cnt,
                                                           float* __restrict__ out) {
    int plane = blockIdx.x;
    int t     = threadIdx.x;
    const float* tp = tiles + (size_t)plane * NT * NT * 3;

    float ssq = 0.0f, tot = 0.0f;
    for (int w = t; w < NWIN * NWIN; w += 256) {
        int wy = w / NWIN, wx = w % NWIN;
        const float* t00 = tp + ((size_t)wy * NT + wx) * 3;
        const float* t10 = t00 + (size_t)NT * 3;
        float s_cc = t00[0] + t00[3] + t10[0] + t10[3];
        float s_ce = t00[1] + t00[4] + t10[1] + t10[4];
        float s_ee = t00[2] + t00[5] + t10[2] + t10[5];
        float a2v = (s_ee > EPSV) ? (s_ce * s_ce / s_ee) : 0.0f;
        ssq += s_cc - a2v;
        tot += s_cc;
    }

    #pragma unroll
    for (int d = 1; d < 64; d <<= 1) {
        ssq += __shfl_xor(ssq, d);
        tot += __shfl_xor(tot, d);
    }
    __shared__ float sr[8];
    __shared__ int   sflag;
    int lane = t & 63, wave = t >> 6;
    if (lane == 0) { sr[wave] = ssq; sr[4 + wave] = tot; }
    __syncthreads();

    if (t == 0) {
        float S = sr[0] + sr[1] + sr[2] + sr[3];
        float T = sr[4] + sr[5] + sr[6] + sr[7];
        acc[plane] = S / T;
        __threadfence();                     // release acc[plane]
        sflag = (atomicAdd(cnt, 1) == NBC - 1);
    }
    __syncthreads();
    if (!sflag) return;

    __threadfence();                         // acquire peers' acc
    if (t < 64) {
        float r = (t < NBC) ? *(volatile const float*)(acc + t) : 0.0f;
        #pragma unroll
        for (int d = 1; d < 64; d <<= 1) r += __shfl_xor(r, d);
        if (t == 0) out[0] = r / (float)NBC;
    }
}

extern "C" void kernel_launch(void* const* d_in, const int* in_sizes, int n_in,
                              void* d_out, int out_size, void* d_ws, size_t ws_size,
                              hipStream_t stream) {
    const float* correct  = (const float*)d_in[0];
    const float* estimate = (const float*)d_in[1];
    const float* mask     = (const float*)d_in[2];
    float* out = (float*)d_out;

    int*   cnt   = (int*)d_ws;                   // 1 int
    float* acc   = (float*)d_ws + 64;            // 48 floats
    float* tiles = (float*)d_ws + 128;           // 48*51*51*3 floats ~ 1.5 MB

    tile_kernel<<<GRID1, 256, 0, stream>>>(correct, estimate, mask, tiles, cnt);
    window_final_kernel<<<NBC, 256, 0, stream>>>(tiles, acc, cnt, out);
}

// Round 7
// 35.881 us; speedup vs baseline: 9.5402x; 1.0308x over previous
//
#include <hip/hip_runtime.h>
#include <hip/hip_bf16.h>

#define HWDIM 512
#define NWIN 50        // windows per dim: (512-20)/10 + 1
#define NT 51          // 10x10 tiles per dim covering rows/cols 0..509
#define NBC 48         // B*C = 16*3
#define NSTRIPE (NBC * NT)   // 2448
#define GRID1 (NSTRIPE / 2)  // 1224 blocks, 2 stripes each (uniform)
#define EPSV 1e-5f

// ws layout: [0] int cnt; floats [64..111] acc[48]; [128..] tiles4[48*51*51] float4

// ---------------------------------------------------------------------------
// Pass 1: per-(plane, 10-row stripe) tile sums; 2 stripes per block.
// Thread t: col4 = t&127 (cols 4c..4c+3), row-half rh = t>>7, rows 2*it+rh.
// Tile-split pattern repeats every 5 float4s per 2 tiles; f=c4%5: f=0,1 all
// in tile 2k; f=2 splits lo/hi; f=3,4 in tile 2k+1.
// Tile records padded to float4 {s_cc, s_ce, s_ee, 0} for pass-2 vector loads.
// ---------------------------------------------------------------------------
__global__ __launch_bounds__(256) void tile_kernel(const float* __restrict__ C,
                                                   const float* __restrict__ E,
                                                   const float* __restrict__ M,
                                                   float4* __restrict__ tiles4,
                                                   int* __restrict__ cnt) {
    int t = threadIdx.x;
    if (blockIdx.x == 0 && t == 0) *cnt = 0;   // for pass-2 last-arriver

    int c4    = t & 127;
    int rh    = t >> 7;
    bool isf2 = ((c4 % 5) == 2);

    __shared__ float lds[2][256 * 6];

    #pragma unroll
    for (int half = 0; half < 2; ++half) {
        int s     = blockIdx.x + half * GRID1;   // stripe id = plane*NT + ty
        int plane = s / NT;
        int ty    = s % NT;
        size_t base = ((size_t)plane * HWDIM + (size_t)ty * 10 + rh) * HWDIM + 4 * c4;

        float4 cv[5], ev[5], mv[5];
        #pragma unroll
        for (int it = 0; it < 5; ++it) {
            size_t o = base + (size_t)(2 * it) * HWDIM;
            cv[it] = *(const float4*)(C + o);
            ev[it] = *(const float4*)(E + o);
            mv[it] = *(const float4*)(M + o);
        }

        float s01[3] = {0.f, 0.f, 0.f};
        float s23[3] = {0.f, 0.f, 0.f};
        #pragma unroll
        for (int it = 0; it < 5; ++it) {
            float4 c = cv[it], e = ev[it], m = mv[it];
            float mcx = m.x * c.x, mcy = m.y * c.y, mcz = m.z * c.z, mcw = m.w * c.w;
            float mex = m.x * e.x, mey = m.y * e.y, mez = m.z * e.z, mew = m.w * e.w;
            s01[0] = fmaf(mcx, c.x, s01[0]); s01[0] = fmaf(mcy, c.y, s01[0]);
            s01[1] = fmaf(mcx, e.x, s01[1]); s01[1] = fmaf(mcy, e.y, s01[1]);
            s01[2] = fmaf(mex, e.x, s01[2]); s01[2] = fmaf(mey, e.y, s01[2]);
            s23[0] = fmaf(mcz, c.z, s23[0]); s23[0] = fmaf(mcw, c.w, s23[0]);
            s23[1] = fmaf(mcz, e.z, s23[1]); s23[1] = fmaf(mcw, e.w, s23[1]);
            s23[2] = fmaf(mez, e.z, s23[2]); s23[2] = fmaf(mew, e.w, s23[2]);
        }

        #pragma unroll
        for (int comp = 0; comp < 3; ++comp) {
            float lo = s01[comp] + (isf2 ? 0.f : s23[comp]);
            float hi = isf2 ? s23[comp] : 0.f;
            lds[half][t * 6 + comp]     = lo;
            lds[half][t * 6 + 3 + comp] = hi;
        }
    }
    __syncthreads();

    // 102 (half, tile) outputs; one float4 store each.
    if (t < 2 * NT) {
        int half = t / NT;
        int tx   = t % NT;
        int k    = tx >> 1;
        const float* L = lds[half];
        float sums[3];
        #pragma unroll
        for (int comp = 0; comp < 3; ++comp) {
            float s;
            if ((tx & 1) == 0) {
                int b = 5 * k;
                s = L[b * 6 + comp] + L[(b + 1) * 6 + comp] + L[(b + 2) * 6 + comp]
                  + L[(b + 128) * 6 + comp] + L[(b + 129) * 6 + comp] + L[(b + 130) * 6 + comp];
            } else {
                int b = 5 * k + 2;
                s = L[b * 6 + 3 + comp] + L[(b + 1) * 6 + comp] + L[(b + 2) * 6 + comp]
                  + L[(b + 128) * 6 + 3 + comp] + L[(b + 129) * 6 + comp] + L[(b + 130) * 6 + comp];
            }
            sums[comp] = s;
        }
        int s_ = blockIdx.x + half * GRID1;
        tiles4[(size_t)s_ * NT + tx] = make_float4(sums[0], sums[1], sums[2], 0.f);
    }
}

// ---------------------------------------------------------------------------
// Pass 2 (fused window + final): 48 blocks, one per plane. Stage the plane's
// 51x51 float4 tile grid in LDS via one coalesced burst, then compute all
// 2500 windows from LDS (fully unrolled). Last-arriving block computes the
// deterministic fixed-order 48-way mean.
// ---------------------------------------------------------------------------
__global__ __launch_bounds__(256) void window_final_kernel(const float4* __restrict__ tiles4,
                                                           float* __restrict__ acc,
                                                           int* __restrict__ cnt,
                                                           float* __restrict__ out) {
    int plane = blockIdx.x;
    int t     = threadIdx.x;

    __shared__ float4 lt[NT * NT];               // 41616 B
    const float4* tp4 = tiles4 + (size_t)plane * NT * NT;
    #pragma unroll
    for (int k = 0; k < 11; ++k) {               // 11*256 >= 2601
        int i = t + k * 256;
        if (i < NT * NT) lt[i] = tp4[i];
    }
    __syncthreads();

    float ssq = 0.0f, tot = 0.0f;
    #pragma unroll
    for (int k = 0; k < 10; ++k) {               // 10*256 >= 2500
        int w = t + k * 256;
        if (w < NWIN * NWIN) {
            int wy = w / NWIN, wx = w % NWIN;
            float4 a = lt[wy * NT + wx];
            float4 b = lt[wy * NT + wx + 1];
            float4 c = lt[(wy + 1) * NT + wx];
            float4 d = lt[(wy + 1) * NT + wx + 1];
            float s_cc = a.x + b.x + c.x + d.x;
            float s_ce = a.y + b.y + c.y + d.y;
            float s_ee = a.z + b.z + c.z + d.z;
            float a2v = (s_ee > EPSV) ? (s_ce * s_ce / s_ee) : 0.0f;
            ssq += s_cc - a2v;
            tot += s_cc;
        }
    }

    #pragma unroll
    for (int d = 1; d < 64; d <<= 1) {
        ssq += __shfl_xor(ssq, d);
        tot += __shfl_xor(tot, d);
    }
    __shared__ float sr[8];
    __shared__ int   sflag;
    int lane = t & 63, wave = t >> 6;
    if (lane == 0) { sr[wave] = ssq; sr[4 + wave] = tot; }
    __syncthreads();

    if (t == 0) {
        float S = sr[0] + sr[1] + sr[2] + sr[3];
        float T = sr[4] + sr[5] + sr[6] + sr[7];
        acc[plane] = S / T;
        __threadfence();                     // release acc[plane]
        sflag = (atomicAdd(cnt, 1) == NBC - 1);
    }
    __syncthreads();
    if (!sflag) return;

    __threadfence();                         // acquire peers' acc
    if (t < 64) {
        float r = (t < NBC) ? *(volatile const float*)(acc + t) : 0.0f;
        #pragma unroll
        for (int d = 1; d < 64; d <<= 1) r += __shfl_xor(r, d);
        if (t == 0) out[0] = r / (float)NBC;
    }
}

extern "C" void kernel_launch(void* const* d_in, const int* in_sizes, int n_in,
                              void* d_out, int out_size, void* d_ws, size_t ws_size,
                              hipStream_t stream) {
    const float* correct  = (const float*)d_in[0];
    const float* estimate = (const float*)d_in[1];
    const float* mask     = (const float*)d_in[2];
    float* out = (float*)d_out;

    int*    cnt    = (int*)d_ws;                 // 1 int
    float*  acc    = (float*)d_ws + 64;          // 48 floats
    float4* tiles4 = (float4*)((float*)d_ws + 128); // 48*51*51 float4 ~ 2.0 MB

    tile_kernel<<<GRID1, 256, 0, stream>>>(correct, estimate, mask, tiles4, cnt);
    window_final_kernel<<<NBC, 256, 0, stream>>>(tiles4, acc, cnt, out);
}